// Round 5
// baseline (313.698 us; speedup 1.0000x reference)
//
#include <hip/hip_runtime.h>
#include <hip/hip_bf16.h>
#include <stdint.h>
#include <stddef.h>

#define DEV static __device__ __forceinline__

typedef __attribute__((ext_vector_type(8))) short short8;   // 8 bf16 (4 VGPRs) MFMA A/B frag
typedef __attribute__((ext_vector_type(4))) float floatx4;  // MFMA C/D frag

constexpr int Tn = 4096, Dn = 512;
constexpr int NC = 128, CTm = 32;   // scan: 128 chunks of 32 along T

union U8s { uint4 u4; unsigned short us[8]; };
union U4f { float4 f4; float f[4]; };
union U4s { uint2 u2; unsigned short us[4]; };

DEV float b2f(unsigned short u) {
  union { unsigned int i; float f; } c; c.i = ((unsigned int)u) << 16; return c.f;
}
DEV unsigned short f2b(float f) {  // RNE float->bf16
  union { float f; unsigned int u; } c; c.f = f;
  unsigned int r = c.u + 0x7fffu + ((c.u >> 16) & 1u);
  return (unsigned short)(r >> 16);
}
DEV float fast_tanh(float x) {     // robust at +/-inf: 1-2/(e^{2x}+1)
  float e = __expf(2.0f * x);
  return 1.0f - 2.0f / (e + 1.0f);
}

typedef __attribute__((address_space(1))) void GVOID;
typedef __attribute__((address_space(3))) void LVOID;
DEV void async16(const unsigned short* g, unsigned short* l) {
  __builtin_amdgcn_global_load_lds((GVOID*)g, (LVOID*)l, 16, 0, 0);
}

// ---------------- scan pass 1: per-chunk partial sums (fp32) ----------------
__global__ void k_scan_partial(const float* __restrict__ dec, float* __restrict__ part) {
  int idx = blockIdx.x * 256 + threadIdx.x;   // B*NC*(D/4) = 131072 threads
  int d4 = idx & 127;
  int c  = (idx >> 7) & (NC - 1);
  int b  = idx >> 14;
  const float* p = dec + ((size_t)b * Tn + (size_t)c * CTm) * Dn + d4 * 4;
  float s[4] = {0,0,0,0};
#pragma unroll 4
  for (int i = 0; i < CTm; ++i) {
    U4f v; v.f4 = *(const float4*)(p + (size_t)i * Dn);
#pragma unroll
    for (int j = 0; j < 4; ++j) s[j] += v.f[j];
  }
  float* o = part + ((size_t)(b * NC + c)) * Dn + d4 * 4;
#pragma unroll
  for (int j = 0; j < 4; ++j) o[j] = s[j];
}

// ------- scan pass 2: LDS parallel exclusive prefix over 128 chunks ---------
// grid 64: block = (b, 64-col group). Hillis-Steele over c in LDS.
__global__ void k_prefix(const float* __restrict__ part, float* __restrict__ P) {
  int b = blockIdx.x >> 3, dg = blockIdx.x & 7;
  __shared__ float S[NC * 64];
  const float* src = part + (size_t)b * NC * Dn + dg * 64;
#pragma unroll
  for (int l = 0; l < 32; ++l) {
    int lin = l * 256 + threadIdx.x;
    int c = lin >> 6, d = lin & 63;
    S[c * 64 + d] = src[(size_t)c * Dn + d];
  }
  __syncthreads();
  for (int off = 1; off < NC; off <<= 1) {
    float t[32];
#pragma unroll
    for (int l = 0; l < 32; ++l) {
      int lin = l * 256 + threadIdx.x;
      int c = lin >> 6, d = lin & 63;
      t[l] = (c >= off) ? S[(c - off) * 64 + d] : 0.f;
    }
    __syncthreads();
#pragma unroll
    for (int l = 0; l < 32; ++l) {
      int lin = l * 256 + threadIdx.x;
      int c = lin >> 6, d = lin & 63;
      S[c * 64 + d] += t[l];
    }
    __syncthreads();
  }
  float* dst = P + (size_t)b * NC * Dn + dg * 64;
#pragma unroll
  for (int l = 0; l < 32; ++l) {
    int lin = l * 256 + threadIdx.x;
    int c = lin >> 6, d = lin & 63;
    dst[(size_t)c * Dn + d] = (c > 0) ? S[(c - 1) * 64 + d] : 0.f;   // exclusive
  }
}

// -------- scan pass 3: running mean -> bf16 M (d4-granular, 8 waves/CU) -----
__global__ void k_scan_apply(const float* __restrict__ dec,
                             const float* __restrict__ P,
                             unsigned short* __restrict__ M) {
  int idx = blockIdx.x * 256 + threadIdx.x;   // B*NC*(D/4) = 131072 threads
  int d4 = idx & 127;
  int c  = (idx >> 7) & (NC - 1);
  int b  = idx >> 14;
  size_t rbase = (size_t)b * Tn + (size_t)c * CTm;
  U4f pv; pv.f4 = *(const float4*)(P + ((size_t)(b * NC + c)) * Dn + d4 * 4);
  float s[4] = {pv.f[0], pv.f[1], pv.f[2], pv.f[3]};
  int t0 = c * CTm;
#pragma unroll 4
  for (int i = 0; i < CTm; ++i) {
    U4f v; v.f4 = *(const float4*)(dec + (rbase + i) * Dn + d4 * 4);
    U4s o;
    float inv = 1.0f / (float)(t0 + i + 1);
#pragma unroll
    for (int j = 0; j < 4; ++j) { s[j] += v.f[j]; o.us[j] = f2b(s[j] * inv); }
    *(uint2*)(M + (rbase + i) * Dn + d4 * 4) = o.u2;
  }
}

// ------- spo[b][n] = bo[n] + sum_j summ[b][j] * W1WoT[n][j]  (wave/output) --
__global__ void k_svec(const float* __restrict__ summ,
                       const unsigned short* __restrict__ W1WoT,
                       const float* __restrict__ bo,
                       float* __restrict__ spo) {
  int widx = blockIdx.x * 4 + (threadIdx.x >> 6);   // 4096 waves total
  int lane = threadIdx.x & 63;
  int n = widx & 511; int b = widx >> 9;
  U8s w8; w8.u4 = *(const uint4*)(W1WoT + (size_t)n * Dn + lane * 8);
  U4f s0, s1;
  s0.f4 = *(const float4*)(summ + (size_t)b * Dn + lane * 8);
  s1.f4 = *(const float4*)(summ + (size_t)b * Dn + lane * 8 + 4);
  float acc = 0.f;
#pragma unroll
  for (int j = 0; j < 4; ++j) acc += s0.f[j] * b2f(w8.us[j]);
#pragma unroll
  for (int j = 0; j < 4; ++j) acc += s1.f[j] * b2f(w8.us[j + 4]);
#pragma unroll
  for (int o = 32; o > 0; o >>= 1) acc += __shfl_xor(acc, o, 64);
  if (lane == 0) spo[(size_t)b * Dn + n] = acc + bo[n];
}

// ---- weight prep, one dispatch: WhT, WoT (transpose), W1b, W2b (convert) ---
__global__ void k_wprep(const float* __restrict__ Wh, const float* __restrict__ Wo,
                        const float* __restrict__ W1, const float* __restrict__ W2,
                        unsigned short* __restrict__ WhT, unsigned short* __restrict__ WoT,
                        unsigned short* __restrict__ W1b, unsigned short* __restrict__ W2b) {
  int blk = blockIdx.x;
  if (blk < 128) {          // transpose section
    const float* in = (blk < 64) ? Wh : Wo;
    unsigned short* out = (blk < 64) ? WhT : WoT;
    int lb = blk & 63;
    __shared__ float t[64][65];
    int n0 = (lb & 7) * 64, k0 = (lb >> 3) * 64;
#pragma unroll
    for (int l = 0; l < 16; ++l) {
      int lin = l * 256 + threadIdx.x;
      int r = lin >> 6, c = lin & 63;
      t[r][c] = in[(size_t)(k0 + r) * 512 + n0 + c];
    }
    __syncthreads();
#pragma unroll
    for (int l = 0; l < 16; ++l) {
      int lin = l * 256 + threadIdx.x;
      int r = lin >> 6, c = lin & 63;
      out[(size_t)(n0 + r) * 512 + k0 + c] = f2b(t[c][r]);
    }
  } else {                  // convert section
    const float* in = (blk < 160) ? W1 : W2;
    unsigned short* out = (blk < 160) ? W1b : W2b;
    int lb = (blk - 128) & 31;
    size_t base = ((size_t)lb * 256 + threadIdx.x) * 32;
#pragma unroll
    for (int l = 0; l < 8; ++l) {
      U4f v; v.f4 = *(const float4*)(in + base + l * 4);
      U4s o;
#pragma unroll
      for (int j = 0; j < 4; ++j) o.us[j] = f2b(v.f[j]);
      *(uint2*)(out + base + l * 4) = o.u2;
    }
  }
}

// ---------------- MFMA GEMM core: C[m][n] = epi(sum_k A[m][k]*BT[n][k]) -----
// EPI 0: tanh(acc + bias[n]) ; EPI 2: acc
template<int EPI>
DEV void gemm_core(const unsigned short* __restrict__ A, const unsigned short* __restrict__ BT,
                   unsigned short* __restrict__ C, const float* __restrict__ bias,
                   int m0, int n0) {
  __shared__ alignas(16) unsigned short sA[128 * 64];
  __shared__ alignas(16) unsigned short sB[128 * 64];
  const int tid  = threadIdx.x;
  const int lane = tid & 63;
  const int w    = tid >> 6;
  const int wm   = (w >> 1) * 64;
  const int wn   = (w & 1) * 64;
  const int rs   = lane & 15;
  const int quad = lane >> 4;

  floatx4 acc[4][4];
#pragma unroll
  for (int i = 0; i < 4; ++i)
#pragma unroll
    for (int j = 0; j < 4; ++j) acc[i][j] = (floatx4){0.f, 0.f, 0.f, 0.f};

  for (int kt = 0; kt < 512; kt += 64) {
#pragma unroll
    for (int l = 0; l < 4; ++l) {
      int ch = l * 256 + tid;
      int r = ch >> 3, kc = ch & 7;
      async16(A  + (size_t)(m0 + r) * 512 + kt + kc * 8, sA + (size_t)ch * 8);
      async16(BT + (size_t)(n0 + r) * 512 + kt + kc * 8, sB + (size_t)ch * 8);
    }
    asm volatile("s_waitcnt vmcnt(0)" ::: "memory");
    __syncthreads();

#pragma unroll
    for (int kk = 0; kk < 2; ++kk) {
      const int kb = kk * 32 + quad * 8;   // A-frag layout: A[m=rs][k=quad*8+j]
      short8 af[4], bfr[4];
#pragma unroll
      for (int i = 0; i < 4; ++i)
        af[i] = *(const short8*)(sA + (size_t)(wm + i * 16 + rs) * 64 + kb);
#pragma unroll
      for (int j = 0; j < 4; ++j)
        bfr[j] = *(const short8*)(sB + (size_t)(wn + j * 16 + rs) * 64 + kb);
#pragma unroll
      for (int i = 0; i < 4; ++i)
#pragma unroll
        for (int j = 0; j < 4; ++j)
          acc[i][j] = __builtin_amdgcn_mfma_f32_16x16x32_bf16(af[i], bfr[j], acc[i][j], 0, 0, 0);
    }
    __syncthreads();
  }

  // C/D layout: col = lane&15, row = quad*4 + reg
#pragma unroll
  for (int i = 0; i < 4; ++i) {
#pragma unroll
    for (int j = 0; j < 4; ++j) {
      const int colg = n0 + wn + j * 16 + rs;
#pragma unroll
      for (int r = 0; r < 4; ++r) {
        const int rowg = m0 + wm + i * 16 + quad * 4 + r;
        float v = acc[i][j][r];
        if constexpr (EPI == 0) v = fast_tanh(v + bias[colg]);
        C[(size_t)rowg * 512 + colg] = f2b(v);
      }
    }
  }
}

template<int EPI>
__global__ __launch_bounds__(256, 2)
void k_gemm(const unsigned short* __restrict__ A, const unsigned short* __restrict__ BT,
            unsigned short* __restrict__ C, const float* __restrict__ bias) {
  gemm_core<EPI>(A, BT, C, bias, blockIdx.x * 128, blockIdx.y * 128);
}

// Both weight GEMMs in one dispatch: z=0 -> W2WoT, z=1 -> W1WoT  (A = WoT)
__global__ __launch_bounds__(256, 2)
void k_wgemm(const unsigned short* __restrict__ WoT,
             const unsigned short* __restrict__ W2b, const unsigned short* __restrict__ W1b,
             unsigned short* __restrict__ W2WoT, unsigned short* __restrict__ W1WoT) {
  const unsigned short* BT = blockIdx.z ? W1b : W2b;
  unsigned short* C = blockIdx.z ? W1WoT : W2WoT;
  gemm_core<2>(WoT, BT, C, nullptr, blockIdx.x * 128, blockIdx.y * 128);
}

// ------- fused GEMM2 + residual + LayerNorm, fp32 out -----------------------
// block: 512 thr = 8 waves; block computes rows [m0,m0+64) x ALL 512 cols.
// wave w = col-group cg: cols cg*64 + [0,64). F stays in regs; LN via LDS.
__global__ __launch_bounds__(512, 4)
void k_gemm2ln(const unsigned short* __restrict__ H, const unsigned short* __restrict__ BT,
               const float* __restrict__ spo, const float* __restrict__ dec,
               const float* __restrict__ gamma, const float* __restrict__ beta,
               float* __restrict__ out) {
  __shared__ alignas(16) unsigned short sA[64 * 64];    // 8 KB  (H tile)
  __shared__ alignas(16) unsigned short sB[512 * 64];   // 64 KB (full-N BT k-slice)
  const int tid  = threadIdx.x;
  const int lane = tid & 63;
  const int cg   = tid >> 6;         // wave index = col group
  const int m0   = blockIdx.x * 64;
  const int b    = blockIdx.x >> 6;  // batch (4096 rows per b)
  const int rs   = lane & 15;
  const int quad = lane >> 4;

  floatx4 acc[4][4];
#pragma unroll
  for (int i = 0; i < 4; ++i)
#pragma unroll
    for (int j = 0; j < 4; ++j) acc[i][j] = (floatx4){0.f, 0.f, 0.f, 0.f};

  for (int kt = 0; kt < 512; kt += 64) {
    {  // sA: 512 16B chunks, one per thread
      int r = tid >> 3, kc = tid & 7;
      async16(H + (size_t)(m0 + r) * 512 + kt + kc * 8, sA + (size_t)tid * 8);
    }
#pragma unroll
    for (int l = 0; l < 8; ++l) {   // sB: 4096 chunks
      int ch = l * 512 + tid;
      int r = ch >> 3, kc = ch & 7;
      async16(BT + (size_t)r * 512 + kt + kc * 8, sB + (size_t)ch * 8);
    }
    asm volatile("s_waitcnt vmcnt(0)" ::: "memory");
    __syncthreads();

#pragma unroll
    for (int kk = 0; kk < 2; ++kk) {
      const int kb = kk * 32 + quad * 8;
      short8 af[4], bfr[4];
#pragma unroll
      for (int i = 0; i < 4; ++i)
        af[i] = *(const short8*)(sA + (size_t)(i * 16 + rs) * 64 + kb);
#pragma unroll
      for (int j = 0; j < 4; ++j)
        bfr[j] = *(const short8*)(sB + (size_t)(cg * 64 + j * 16 + rs) * 64 + kb);
#pragma unroll
      for (int i = 0; i < 4; ++i)
#pragma unroll
        for (int j = 0; j < 4; ++j)
          acc[i][j] = __builtin_amdgcn_mfma_f32_16x16x32_bf16(af[i], bfr[j], acc[i][j], 0, 0, 0);
    }
    __syncthreads();
  }

  // ---- epilogue: x = tanh(spo - acc) + dec; LN over 512 cols per row ----
  float* redS = (float*)sA;          // 64 rows x 8 cg
  float* redQ = redS + 512;
  float* muL  = redQ + 512;
  float* rsL  = muL + 64;

  float spo_v[4], gam_v[4], bet_v[4];
#pragma unroll
  for (int j = 0; j < 4; ++j) {
    int col = cg * 64 + j * 16 + rs;
    spo_v[j] = spo[(size_t)b * 512 + col];
    gam_v[j] = gamma[col];
    bet_v[j] = beta[col];
  }

  float ps[4][4], ps2[4][4];
#pragma unroll
  for (int i = 0; i < 4; ++i)
#pragma unroll
    for (int r = 0; r < 4; ++r) { ps[i][r] = 0.f; ps2[i][r] = 0.f; }

#pragma unroll
  for (int i = 0; i < 4; ++i)
#pragma unroll
    for (int j = 0; j < 4; ++j) {
      const int colg = cg * 64 + j * 16 + rs;
#pragma unroll
      for (int r = 0; r < 4; ++r) {
        const int rowg = m0 + i * 16 + quad * 4 + r;
        float x = fast_tanh(spo_v[j] - acc[i][j][r]) + dec[(size_t)rowg * 512 + colg];
        acc[i][j][r] = x;
        ps[i][r] += x; ps2[i][r] += x * x;
      }
    }
  // reduce over the 16 lanes of each quad (cols within this wave)
#pragma unroll
  for (int off = 1; off < 16; off <<= 1)
#pragma unroll
    for (int i = 0; i < 4; ++i)
#pragma unroll
      for (int r = 0; r < 4; ++r) {
        ps[i][r]  += __shfl_xor(ps[i][r],  off, 64);
        ps2[i][r] += __shfl_xor(ps2[i][r], off, 64);
      }
  if (rs == 0) {
#pragma unroll
    for (int i = 0; i < 4; ++i)
#pragma unroll
      for (int r = 0; r < 4; ++r) {
        int rl = i * 16 + quad * 4 + r;
        redS[rl * 8 + cg] = ps[i][r];
        redQ[rl * 8 + cg] = ps2[i][r];
      }
  }
  __syncthreads();
  if (tid < 64) {
    float s = 0.f, q = 0.f;
#pragma unroll
    for (int g = 0; g < 8; ++g) { s += redS[tid * 8 + g]; q += redQ[tid * 8 + g]; }
    float mu = s * (1.0f / 512.0f);
    float var = q * (1.0f / 512.0f) - mu * mu;
    muL[tid] = mu;
    rsL[tid] = rsqrtf(var + 1e-6f);
  }
  __syncthreads();
#pragma unroll
  for (int i = 0; i < 4; ++i)
#pragma unroll
    for (int r = 0; r < 4; ++r) {
      int rl = i * 16 + quad * 4 + r;
      float mu = muL[rl], rstd = rsL[rl];
#pragma unroll
      for (int j = 0; j < 4; ++j) {
        int colg = cg * 64 + j * 16 + rs;
        out[(size_t)(m0 + rl) * 512 + colg] = (acc[i][j][r] - mu) * rstd * gam_v[j] + bet_v[j];
      }
    }
}

extern "C" void kernel_launch(void* const* d_in, const int* in_sizes, int n_in,
                              void* d_out, int out_size, void* d_ws, size_t ws_size,
                              hipStream_t stream) {
  (void)in_sizes; (void)n_in; (void)out_size; (void)ws_size;
  const float* summ = (const float*)d_in[0];
  const float* dec  = (const float*)d_in[1];
  const float* Wh   = (const float*)d_in[2];
  const float* bh   = (const float*)d_in[3];
  const float* W1   = (const float*)d_in[4];
  const float* W2   = (const float*)d_in[5];
  const float* Wo   = (const float*)d_in[6];
  const float* bo   = (const float*)d_in[7];
  const float* gam  = (const float*)d_in[8];
  const float* bet  = (const float*)d_in[9];
  float* out = (float*)d_out;

  char* ws = (char*)d_ws;
  unsigned short* Mbuf  = (unsigned short*)(ws);                 // 32 MB bf16 M
  unsigned short* Hbuf  = (unsigned short*)(ws + 33554432);      // 32 MB bf16 H
  float*          pfix  = (float*)(ws + 33554432);               // 2 MB, ALIASES Hbuf:
                                                                 // consumed by k_scan_apply before k_gemm<0> writes H
  float*          part  = (float*)(ws + 67108864);               // 2 MB fp32 chunk sums
  float*          spo   = (float*)(ws + 69206016);               // 16 KB
  unsigned short* WhT   = (unsigned short*)(ws + 69238784);      // 512 KB bf16
  unsigned short* WoT   = (unsigned short*)(ws + 69763072);      // 512 KB bf16
  unsigned short* W2b   = (unsigned short*)(ws + 70287360);      // 512 KB bf16
  unsigned short* W2WoT = (unsigned short*)(ws + 70811648);      // 512 KB bf16
  unsigned short* W1b   = (unsigned short*)(ws + 71335936);      // 512 KB bf16
  unsigned short* W1WoT = (unsigned short*)(ws + 71860224);      // 512 KB bf16

  // chunk sums for the scan (independent of weight prep)
  k_scan_partial<<<512, 256, 0, stream>>>(dec, part);

  // weight prep + both weight GEMMs + summarization vector
  k_wprep<<<192, 256, 0, stream>>>(Wh, Wo, W1, W2, WhT, WoT, W1b, W2b);
  k_wgemm<<<dim3(4, 4, 2), 256, 0, stream>>>(WoT, W2b, W1b, W2WoT, W1WoT);
  k_svec<<<1024, 256, 0, stream>>>(summ, W1WoT, bo, spo);

  // scan: LDS-parallel exclusive chunk prefix, then running mean -> M
  k_prefix<<<64, 256, 0, stream>>>(part, pfix);
  k_scan_apply<<<512, 256, 0, stream>>>(dec, pfix, Mbuf);

  // H = tanh(M @ Wh + bh)
  k_gemm<0><<<dim3(256, 4), 256, 0, stream>>>(Mbuf, WhT, Hbuf, bh);
  // out = LN(tanh(spo - H @ W2Wo) + dec) * gamma + beta   (fused, F never hits HBM)
  k_gemm2ln<<<512, 512, 0, stream>>>(Hbuf, W2WoT, spo, dec, gam, bet, out);
}

// Round 6
// 277.731 us; speedup vs baseline: 1.1295x; 1.1295x over previous
//
#include <hip/hip_runtime.h>
#include <hip/hip_bf16.h>
#include <stdint.h>
#include <stddef.h>

#define DEV static __device__ __forceinline__

typedef __attribute__((ext_vector_type(8))) short short8;   // 8 bf16 (4 VGPRs) MFMA A/B frag
typedef __attribute__((ext_vector_type(4))) float floatx4;  // MFMA C/D frag

constexpr int Tn = 4096, Dn = 512;
constexpr int NC = 128, CTm = 32;   // scan: 128 chunks of 32 along T

union U8s { uint4 u4; unsigned short us[8]; };
union U4f { float4 f4; float f[4]; };
union U4s { uint2 u2; unsigned short us[4]; };

DEV float b2f(unsigned short u) {
  union { unsigned int i; float f; } c; c.i = ((unsigned int)u) << 16; return c.f;
}
DEV unsigned short f2b(float f) {  // RNE float->bf16
  union { float f; unsigned int u; } c; c.f = f;
  unsigned int r = c.u + 0x7fffu + ((c.u >> 16) & 1u);
  return (unsigned short)(r >> 16);
}
DEV float fast_tanh(float x) {     // robust at +/-inf: 1-2/(e^{2x}+1)
  float e = __expf(2.0f * x);
  return 1.0f - 2.0f / (e + 1.0f);
}

typedef __attribute__((address_space(1))) void GVOID;
typedef __attribute__((address_space(3))) void LVOID;
DEV void async16(const unsigned short* g, unsigned short* l) {
  __builtin_amdgcn_global_load_lds((GVOID*)g, (LVOID*)l, 16, 0, 0);
}

// ---------------- scan pass 1: per-chunk partial sums (fp32) ----------------
__global__ void k_scan_partial(const float* __restrict__ dec, float* __restrict__ part) {
  int idx = blockIdx.x * 256 + threadIdx.x;   // B*NC*(D/4) = 131072 threads
  int d4 = idx & 127;
  int c  = (idx >> 7) & (NC - 1);
  int b  = idx >> 14;
  const float* p = dec + ((size_t)b * Tn + (size_t)c * CTm) * Dn + d4 * 4;
  float s[4] = {0,0,0,0};
#pragma unroll 4
  for (int i = 0; i < CTm; ++i) {
    U4f v; v.f4 = *(const float4*)(p + (size_t)i * Dn);
#pragma unroll
    for (int j = 0; j < 4; ++j) s[j] += v.f[j];
  }
  float* o = part + ((size_t)(b * NC + c)) * Dn + d4 * 4;
#pragma unroll
  for (int j = 0; j < 4; ++j) o[j] = s[j];
}

// ------- scan pass 2: LDS parallel exclusive prefix over 128 chunks ---------
__global__ void k_prefix(const float* __restrict__ part, float* __restrict__ P) {
  int b = blockIdx.x >> 3, dg = blockIdx.x & 7;
  __shared__ float S[NC * 64];
  const float* src = part + (size_t)b * NC * Dn + dg * 64;
#pragma unroll
  for (int l = 0; l < 32; ++l) {
    int lin = l * 256 + threadIdx.x;
    int c = lin >> 6, d = lin & 63;
    S[c * 64 + d] = src[(size_t)c * Dn + d];
  }
  __syncthreads();
  for (int off = 1; off < NC; off <<= 1) {
    float t[32];
#pragma unroll
    for (int l = 0; l < 32; ++l) {
      int lin = l * 256 + threadIdx.x;
      int c = lin >> 6, d = lin & 63;
      t[l] = (c >= off) ? S[(c - off) * 64 + d] : 0.f;
    }
    __syncthreads();
#pragma unroll
    for (int l = 0; l < 32; ++l) {
      int lin = l * 256 + threadIdx.x;
      int c = lin >> 6, d = lin & 63;
      S[c * 64 + d] += t[l];
    }
    __syncthreads();
  }
  float* dst = P + (size_t)b * NC * Dn + dg * 64;
#pragma unroll
  for (int l = 0; l < 32; ++l) {
    int lin = l * 256 + threadIdx.x;
    int c = lin >> 6, d = lin & 63;
    dst[(size_t)c * Dn + d] = (c > 0) ? S[(c - 1) * 64 + d] : 0.f;   // exclusive
  }
}

// -------- scan pass 3: running mean -> bf16 M (d4-granular, 8 waves/CU) -----
__global__ void k_scan_apply(const float* __restrict__ dec,
                             const float* __restrict__ P,
                             unsigned short* __restrict__ M) {
  int idx = blockIdx.x * 256 + threadIdx.x;   // B*NC*(D/4) = 131072 threads
  int d4 = idx & 127;
  int c  = (idx >> 7) & (NC - 1);
  int b  = idx >> 14;
  size_t rbase = (size_t)b * Tn + (size_t)c * CTm;
  U4f pv; pv.f4 = *(const float4*)(P + ((size_t)(b * NC + c)) * Dn + d4 * 4);
  float s[4] = {pv.f[0], pv.f[1], pv.f[2], pv.f[3]};
  int t0 = c * CTm;
#pragma unroll 4
  for (int i = 0; i < CTm; ++i) {
    U4f v; v.f4 = *(const float4*)(dec + (rbase + i) * Dn + d4 * 4);
    U4s o;
    float inv = 1.0f / (float)(t0 + i + 1);
#pragma unroll
    for (int j = 0; j < 4; ++j) { s[j] += v.f[j]; o.us[j] = f2b(s[j] * inv); }
    *(uint2*)(M + (rbase + i) * Dn + d4 * 4) = o.u2;
  }
}

// ------- spo[b][n] = bo[n] + sum_j summ[b][j] * W1WoT[n][j]  (wave/output) --
__global__ void k_svec(const float* __restrict__ summ,
                       const unsigned short* __restrict__ W1WoT,
                       const float* __restrict__ bo,
                       float* __restrict__ spo) {
  int widx = blockIdx.x * 4 + (threadIdx.x >> 6);   // 4096 waves total
  int lane = threadIdx.x & 63;
  int n = widx & 511; int b = widx >> 9;
  U8s w8; w8.u4 = *(const uint4*)(W1WoT + (size_t)n * Dn + lane * 8);
  U4f s0, s1;
  s0.f4 = *(const float4*)(summ + (size_t)b * Dn + lane * 8);
  s1.f4 = *(const float4*)(summ + (size_t)b * Dn + lane * 8 + 4);
  float acc = 0.f;
#pragma unroll
  for (int j = 0; j < 4; ++j) acc += s0.f[j] * b2f(w8.us[j]);
#pragma unroll
  for (int j = 0; j < 4; ++j) acc += s1.f[j] * b2f(w8.us[j + 4]);
#pragma unroll
  for (int o = 32; o > 0; o >>= 1) acc += __shfl_xor(acc, o, 64);
  if (lane == 0) spo[(size_t)b * Dn + n] = acc + bo[n];
}

// ---- weight prep, one dispatch: WhT, WoT (transpose), W1b, W2b (convert) ---
__global__ void k_wprep(const float* __restrict__ Wh, const float* __restrict__ Wo,
                        const float* __restrict__ W1, const float* __restrict__ W2,
                        unsigned short* __restrict__ WhT, unsigned short* __restrict__ WoT,
                        unsigned short* __restrict__ W1b, unsigned short* __restrict__ W2b) {
  int blk = blockIdx.x;
  if (blk < 128) {          // transpose section
    const float* in = (blk < 64) ? Wh : Wo;
    unsigned short* out = (blk < 64) ? WhT : WoT;
    int lb = blk & 63;
    __shared__ float t[64][65];
    int n0 = (lb & 7) * 64, k0 = (lb >> 3) * 64;
#pragma unroll
    for (int l = 0; l < 16; ++l) {
      int lin = l * 256 + threadIdx.x;
      int r = lin >> 6, c = lin & 63;
      t[r][c] = in[(size_t)(k0 + r) * 512 + n0 + c];
    }
    __syncthreads();
#pragma unroll
    for (int l = 0; l < 16; ++l) {
      int lin = l * 256 + threadIdx.x;
      int r = lin >> 6, c = lin & 63;
      out[(size_t)(n0 + r) * 512 + k0 + c] = f2b(t[c][r]);
    }
  } else {                  // convert section
    const float* in = (blk < 160) ? W1 : W2;
    unsigned short* out = (blk < 160) ? W1b : W2b;
    int lb = (blk - 128) & 31;
    size_t base = ((size_t)lb * 256 + threadIdx.x) * 32;
#pragma unroll
    for (int l = 0; l < 8; ++l) {
      U4f v; v.f4 = *(const float4*)(in + base + l * 4);
      U4s o;
#pragma unroll
      for (int j = 0; j < 4; ++j) o.us[j] = f2b(v.f[j]);
      *(uint2*)(out + base + l * 4) = o.u2;
    }
  }
}

// ---------------- MFMA GEMM core: C[m][n] = epi(sum_k A[m][k]*BT[n][k]) -----
// EPI 0: tanh(acc + bias[n]) ; EPI 2: acc
template<int EPI>
DEV void gemm_core(const unsigned short* __restrict__ A, const unsigned short* __restrict__ BT,
                   unsigned short* __restrict__ C, const float* __restrict__ bias,
                   int m0, int n0) {
  __shared__ alignas(16) unsigned short sA[128 * 64];
  __shared__ alignas(16) unsigned short sB[128 * 64];
  const int tid  = threadIdx.x;
  const int lane = tid & 63;
  const int w    = tid >> 6;
  const int wm   = (w >> 1) * 64;
  const int wn   = (w & 1) * 64;
  const int rs   = lane & 15;
  const int quad = lane >> 4;

  floatx4 acc[4][4];
#pragma unroll
  for (int i = 0; i < 4; ++i)
#pragma unroll
    for (int j = 0; j < 4; ++j) acc[i][j] = (floatx4){0.f, 0.f, 0.f, 0.f};

  for (int kt = 0; kt < 512; kt += 64) {
#pragma unroll
    for (int l = 0; l < 4; ++l) {
      int ch = l * 256 + tid;
      int r = ch >> 3, kc = ch & 7;
      async16(A  + (size_t)(m0 + r) * 512 + kt + kc * 8, sA + (size_t)ch * 8);
      async16(BT + (size_t)(n0 + r) * 512 + kt + kc * 8, sB + (size_t)ch * 8);
    }
    asm volatile("s_waitcnt vmcnt(0)" ::: "memory");
    __syncthreads();

#pragma unroll
    for (int kk = 0; kk < 2; ++kk) {
      const int kb = kk * 32 + quad * 8;   // A-frag layout: A[m=rs][k=quad*8+j]
      short8 af[4], bfr[4];
#pragma unroll
      for (int i = 0; i < 4; ++i)
        af[i] = *(const short8*)(sA + (size_t)(wm + i * 16 + rs) * 64 + kb);
#pragma unroll
      for (int j = 0; j < 4; ++j)
        bfr[j] = *(const short8*)(sB + (size_t)(wn + j * 16 + rs) * 64 + kb);
#pragma unroll
      for (int i = 0; i < 4; ++i)
#pragma unroll
        for (int j = 0; j < 4; ++j)
          acc[i][j] = __builtin_amdgcn_mfma_f32_16x16x32_bf16(af[i], bfr[j], acc[i][j], 0, 0, 0);
    }
    __syncthreads();
  }

  // C/D layout: col = lane&15, row = quad*4 + reg
#pragma unroll
  for (int i = 0; i < 4; ++i) {
#pragma unroll
    for (int j = 0; j < 4; ++j) {
      const int colg = n0 + wn + j * 16 + rs;
#pragma unroll
      for (int r = 0; r < 4; ++r) {
        const int rowg = m0 + wm + i * 16 + quad * 4 + r;
        float v = acc[i][j][r];
        if constexpr (EPI == 0) v = fast_tanh(v + bias[colg]);
        C[(size_t)rowg * 512 + colg] = f2b(v);
      }
    }
  }
}

template<int EPI>
__global__ __launch_bounds__(256, 2)
void k_gemm(const unsigned short* __restrict__ A, const unsigned short* __restrict__ BT,
            unsigned short* __restrict__ C, const float* __restrict__ bias) {
  gemm_core<EPI>(A, BT, C, bias, blockIdx.x * 128, blockIdx.y * 128);
}

// Both weight GEMMs in one dispatch: z=0 -> W2WoT, z=1 -> W1WoT  (A = WoT)
__global__ __launch_bounds__(256, 2)
void k_wgemm(const unsigned short* __restrict__ WoT,
             const unsigned short* __restrict__ W2b, const unsigned short* __restrict__ W1b,
             unsigned short* __restrict__ W2WoT, unsigned short* __restrict__ W1WoT) {
  const unsigned short* BT = blockIdx.z ? W1b : W2b;
  unsigned short* C = blockIdx.z ? W1WoT : W2WoT;
  gemm_core<2>(WoT, BT, C, nullptr, blockIdx.x * 128, blockIdx.y * 128);
}

// ------- fused GEMM2 + residual + LayerNorm, fp32 out -----------------------
// block: 512 thr = 8 waves; block computes rows [m0,m0+64) x ALL 512 cols.
// __launch_bounds__(512, 2): VGPR cap 256/lane (the (512,4) cap of 128 caused
// 91 MB of scratch-spill writes in round 5 — 64 AGPR acc + 32 VGPR frags alone
// hit the cap).
__global__ __launch_bounds__(512, 2)
void k_gemm2ln(const unsigned short* __restrict__ H, const unsigned short* __restrict__ BT,
               const float* __restrict__ spo, const float* __restrict__ dec,
               const float* __restrict__ gamma, const float* __restrict__ beta,
               float* __restrict__ out) {
  __shared__ alignas(16) unsigned short sA[64 * 64];    // 8 KB  (H tile)
  __shared__ alignas(16) unsigned short sB[512 * 64];   // 64 KB (full-N BT k-slice)
  const int tid  = threadIdx.x;
  const int lane = tid & 63;
  const int cg   = tid >> 6;         // wave index = col group
  const int m0   = blockIdx.x * 64;
  const int b    = blockIdx.x >> 6;  // batch (4096 rows per b)
  const int rs   = lane & 15;
  const int quad = lane >> 4;

  floatx4 acc[4][4];
#pragma unroll
  for (int i = 0; i < 4; ++i)
#pragma unroll
    for (int j = 0; j < 4; ++j) acc[i][j] = (floatx4){0.f, 0.f, 0.f, 0.f};

  for (int kt = 0; kt < 512; kt += 64) {
    {  // sA: 512 16B chunks, one per thread
      int r = tid >> 3, kc = tid & 7;
      async16(H + (size_t)(m0 + r) * 512 + kt + kc * 8, sA + (size_t)tid * 8);
    }
#pragma unroll
    for (int l = 0; l < 8; ++l) {   // sB: 4096 chunks
      int ch = l * 512 + tid;
      int r = ch >> 3, kc = ch & 7;
      async16(BT + (size_t)r * 512 + kt + kc * 8, sB + (size_t)ch * 8);
    }
    asm volatile("s_waitcnt vmcnt(0)" ::: "memory");
    __syncthreads();

#pragma unroll
    for (int kk = 0; kk < 2; ++kk) {
      const int kb = kk * 32 + quad * 8;
      short8 af[4], bfr[4];
#pragma unroll
      for (int i = 0; i < 4; ++i)
        af[i] = *(const short8*)(sA + (size_t)(i * 16 + rs) * 64 + kb);
#pragma unroll
      for (int j = 0; j < 4; ++j)
        bfr[j] = *(const short8*)(sB + (size_t)(cg * 64 + j * 16 + rs) * 64 + kb);
#pragma unroll
      for (int i = 0; i < 4; ++i)
#pragma unroll
        for (int j = 0; j < 4; ++j)
          acc[i][j] = __builtin_amdgcn_mfma_f32_16x16x32_bf16(af[i], bfr[j], acc[i][j], 0, 0, 0);
    }
    __syncthreads();
  }

  // ---- epilogue: x = tanh(spo - acc) + dec; LN over 512 cols per row ----
  float* redS = (float*)sA;          // 64 rows x 8 cg
  float* redQ = redS + 512;
  float* muL  = redQ + 512;
  float* rsL  = muL + 64;

  float spo_v[4], gam_v[4], bet_v[4];
#pragma unroll
  for (int j = 0; j < 4; ++j) {
    int col = cg * 64 + j * 16 + rs;
    spo_v[j] = spo[(size_t)b * 512 + col];
    gam_v[j] = gamma[col];
    bet_v[j] = beta[col];
  }

  float ps[4][4], ps2[4][4];
#pragma unroll
  for (int i = 0; i < 4; ++i)
#pragma unroll
    for (int r = 0; r < 4; ++r) { ps[i][r] = 0.f; ps2[i][r] = 0.f; }

#pragma unroll
  for (int i = 0; i < 4; ++i)
#pragma unroll
    for (int j = 0; j < 4; ++j) {
      const int colg = cg * 64 + j * 16 + rs;
#pragma unroll
      for (int r = 0; r < 4; ++r) {
        const int rowg = m0 + i * 16 + quad * 4 + r;
        float x = fast_tanh(spo_v[j] - acc[i][j][r]) + dec[(size_t)rowg * 512 + colg];
        acc[i][j][r] = x;
        ps[i][r] += x; ps2[i][r] += x * x;
      }
    }
  // reduce over the 16 lanes of each quad (cols within this wave)
#pragma unroll
  for (int off = 1; off < 16; off <<= 1)
#pragma unroll
    for (int i = 0; i < 4; ++i)
#pragma unroll
      for (int r = 0; r < 4; ++r) {
        ps[i][r]  += __shfl_xor(ps[i][r],  off, 64);
        ps2[i][r] += __shfl_xor(ps2[i][r], off, 64);
      }
  if (rs == 0) {
#pragma unroll
    for (int i = 0; i < 4; ++i)
#pragma unroll
      for (int r = 0; r < 4; ++r) {
        int rl = i * 16 + quad * 4 + r;
        redS[rl * 8 + cg] = ps[i][r];
        redQ[rl * 8 + cg] = ps2[i][r];
      }
  }
  __syncthreads();
  if (tid < 64) {
    float s = 0.f, q = 0.f;
#pragma unroll
    for (int g = 0; g < 8; ++g) { s += redS[tid * 8 + g]; q += redQ[tid * 8 + g]; }
    float mu = s * (1.0f / 512.0f);
    float var = q * (1.0f / 512.0f) - mu * mu;
    muL[tid] = mu;
    rsL[tid] = rsqrtf(var + 1e-6f);
  }
  __syncthreads();
#pragma unroll
  for (int i = 0; i < 4; ++i)
#pragma unroll
    for (int r = 0; r < 4; ++r) {
      int rl = i * 16 + quad * 4 + r;
      float mu = muL[rl], rstd = rsL[rl];
#pragma unroll
      for (int j = 0; j < 4; ++j) {
        int colg = cg * 64 + j * 16 + rs;
        out[(size_t)(m0 + rl) * 512 + colg] = (acc[i][j][r] - mu) * rstd * gam_v[j] + bet_v[j];
      }
    }
}

extern "C" void kernel_launch(void* const* d_in, const int* in_sizes, int n_in,
                              void* d_out, int out_size, void* d_ws, size_t ws_size,
                              hipStream_t stream) {
  (void)in_sizes; (void)n_in; (void)out_size; (void)ws_size;
  const float* summ = (const float*)d_in[0];
  const float* dec  = (const float*)d_in[1];
  const float* Wh   = (const float*)d_in[2];
  const float* bh   = (const float*)d_in[3];
  const float* W1   = (const float*)d_in[4];
  const float* W2   = (const float*)d_in[5];
  const float* Wo   = (const float*)d_in[6];
  const float* bo   = (const float*)d_in[7];
  const float* gam  = (const float*)d_in[8];
  const float* bet  = (const float*)d_in[9];
  float* out = (float*)d_out;

  char* ws = (char*)d_ws;
  unsigned short* Mbuf  = (unsigned short*)(ws);                 // 32 MB bf16 M
  unsigned short* Hbuf  = (unsigned short*)(ws + 33554432);      // 32 MB bf16 H
  float*          pfix  = (float*)(ws + 33554432);               // 2 MB, ALIASES Hbuf:
                                                                 // consumed by k_scan_apply before k_gemm<0> writes H
  float*          part  = (float*)(ws + 67108864);               // 2 MB fp32 chunk sums
  float*          spo   = (float*)(ws + 69206016);               // 16 KB
  unsigned short* WhT   = (unsigned short*)(ws + 69238784);      // 512 KB bf16
  unsigned short* WoT   = (unsigned short*)(ws + 69763072);      // 512 KB bf16
  unsigned short* W2b   = (unsigned short*)(ws + 70287360);      // 512 KB bf16
  unsigned short* W2WoT = (unsigned short*)(ws + 70811648);      // 512 KB bf16
  unsigned short* W1b   = (unsigned short*)(ws + 71335936);      // 512 KB bf16
  unsigned short* W1WoT = (unsigned short*)(ws + 71860224);      // 512 KB bf16

  // chunk sums for the scan (independent of weight prep)
  k_scan_partial<<<512, 256, 0, stream>>>(dec, part);

  // weight prep + both weight GEMMs + summarization vector
  k_wprep<<<192, 256, 0, stream>>>(Wh, Wo, W1, W2, WhT, WoT, W1b, W2b);
  k_wgemm<<<dim3(4, 4, 2), 256, 0, stream>>>(WoT, W2b, W1b, W2WoT, W1WoT);
  k_svec<<<1024, 256, 0, stream>>>(summ, W1WoT, bo, spo);

  // scan: LDS-parallel exclusive chunk prefix, then running mean -> M
  k_prefix<<<64, 256, 0, stream>>>(part, pfix);
  k_scan_apply<<<512, 256, 0, stream>>>(dec, pfix, Mbuf);

  // H = tanh(M @ Wh + bh)
  k_gemm<0><<<dim3(256, 4), 256, 0, stream>>>(Mbuf, WhT, Hbuf, bh);
  // out = LN(tanh(spo - H @ W2Wo) + dec) * gamma + beta   (fused, F never hits HBM)
  k_gemm2ln<<<512, 512, 0, stream>>>(Hbuf, W2WoT, spo, dec, gam, bet, out);
}